// Round 3
// baseline (539.763 us; speedup 1.0000x reference)
//
#include <hip/hip_runtime.h>

// ---------------- problem constants ----------------
#define N_NODES 10000
#define T_STEPS 8
#define F_IN 4
#define H1 16
#define HEADS 4
#define H2 32
#define G 32
#define PW 16
#define E_EDGES 160000
#define ETOT (E_EDGES + N_NODES)   // edges + self loops = 170000

__device__ __forceinline__ float lrelu(float x) { return x > 0.f ? x : 0.2f * x; }
__device__ __forceinline__ float eluf(float x) { return x > 0.f ? x : (expf(x) - 1.f); }
__device__ __forceinline__ float sigmoidf(float x) { return 1.f / (1.f + expf(-x)); }
__device__ __forceinline__ float wmaxf(float v) {
#pragma unroll
    for (int o = 32; o; o >>= 1) v = fmaxf(v, __shfl_xor(v, o));
    return v;
}
__device__ __forceinline__ float wsumf(float v) {
#pragma unroll
    for (int o = 32; o; o >>= 1) v += __shfl_xor(v, o);
    return v;
}

// ---------------- CSR build (counting sort by dst) ----------------
__global__ void k_count(const int* __restrict__ ei, int* __restrict__ cnt) {
    int idx = blockIdx.x * blockDim.x + threadIdx.x;
    if (idx >= ETOT) return;
    int dst = (idx < E_EDGES) ? ei[E_EDGES + idx] : (idx - E_EDGES);
    atomicAdd(&cnt[dst], 1);
}

__global__ void k_scan(const int* __restrict__ cnt, int* __restrict__ rowptr,
                       int* __restrict__ cursor) {
    __shared__ int ssum[256];
    const int CH = (N_NODES + 255) / 256;  // 40
    int tid = threadIdx.x;
    int base = tid * CH;
    int loc = 0;
    for (int i = 0; i < CH; ++i) {
        int idx = base + i;
        if (idx < N_NODES) loc += cnt[idx];
    }
    ssum[tid] = loc;
    __syncthreads();
    for (int st = 1; st < 256; st <<= 1) {
        int v = (tid >= st) ? ssum[tid - st] : 0;
        __syncthreads();
        ssum[tid] += v;
        __syncthreads();
    }
    int run = ssum[tid] - loc;  // exclusive
    for (int i = 0; i < CH; ++i) {
        int idx = base + i;
        if (idx < N_NODES) {
            rowptr[idx] = run;
            cursor[idx] = run;
            run += cnt[idx];
        }
    }
    if (tid == 255) rowptr[N_NODES] = ssum[255];
}

__global__ void k_scatter(const int* __restrict__ ei, int* __restrict__ cursor,
                          int* __restrict__ colsrc) {
    int idx = blockIdx.x * blockDim.x + threadIdx.x;
    if (idx >= ETOT) return;
    int src = (idx < E_EDGES) ? ei[idx] : (idx - E_EDGES);
    int dst = (idx < E_EDGES) ? ei[E_EDGES + idx] : (idx - E_EDGES);
    int pos = atomicAdd(&cursor[dst], 1);
    colsrc[pos] = src;
}

// ---------------- layer 1: projection + attention logits ----------------
// layouts: z1[(n*8+t)*64], asrc1/adst1 float4 at (n*8+t)
__global__ void __launch_bounds__(256) k_l1_proj(
        const float* __restrict__ dyn, const float* __restrict__ W1,
        const float* __restrict__ as1, const float* __restrict__ ad1,
        float* __restrict__ z1, float4* __restrict__ asrc,
        float4* __restrict__ adst) {
    __shared__ float sW[256], sAs[64], sAd[64];
    int tid = threadIdx.x;
    if (tid < 256) sW[tid] = W1[tid];
    if (tid < 64) { sAs[tid] = as1[tid]; sAd[tid] = ad1[tid]; }
    __syncthreads();
    int idx = blockIdx.x * blockDim.x + tid;  // idx = n*8+t  (dyn is [n][t][4])
    if (idx >= T_STEPS * N_NODES) return;
    const float4 xv = *reinterpret_cast<const float4*>(dyn + (size_t)idx * F_IN);
    float* zrow = z1 + (size_t)idx * 64;
    float a_s[HEADS] = {0.f, 0.f, 0.f, 0.f};
    float a_d[HEADS] = {0.f, 0.f, 0.f, 0.f};
    float4 zbuf;
#pragma unroll
    for (int j = 0; j < 64; ++j) {
        float z = xv.x * sW[j] + xv.y * sW[64 + j] + xv.z * sW[128 + j] + xv.w * sW[192 + j];
        ((float*)&zbuf)[j & 3] = z;
        if ((j & 3) == 3) *reinterpret_cast<float4*>(zrow + (j - 3)) = zbuf;
        int h = j >> 4;
        a_s[h] += z * sAs[j];
        a_d[h] += z * sAd[j];
    }
    asrc[idx] = make_float4(a_s[0], a_s[1], a_s[2], a_s[3]);
    adst[idx] = make_float4(a_d[0], a_d[1], a_d[2], a_d[3]);
}

// ---------------- layer 1 gather + fused layer-2 projection ----------------
// one wave per (n,t); 4 waves/block share n. Writes z2[(n*8+t)*32], asrc2/adst2[n*8+t].
__global__ void __launch_bounds__(256) k_l1_gather(
        const int* __restrict__ rowptr, const int* __restrict__ colsrc,
        const float4* __restrict__ asrc, const float4* __restrict__ adst,
        const float* __restrict__ z1, const float* __restrict__ b1,
        const float* __restrict__ W2, const float* __restrict__ as2,
        const float* __restrict__ ad2, float* __restrict__ z2,
        float* __restrict__ asrc2, float* __restrict__ adst2) {
    __shared__ int sSrc[4][64];
    __shared__ float4 sWgt[4][64];
    __shared__ float sRow[4][64];
    __shared__ float sW2[64 * 32];
    __shared__ float sAs2[32], sAd2[32];
    int tid = threadIdx.x;
    for (int i = tid; i < 64 * 32; i += 256) sW2[i] = W2[i];
    if (tid < 32) { sAs2[tid] = as2[tid]; sAd2[tid] = ad2[tid]; }
    __syncthreads();

    int lane = tid & 63;
    int wslot = tid >> 6;
    int wid = blockIdx.x * 4 + wslot;           // == n*8+t
    int n = wid >> 3, t = wid & 7;
    int beg = rowptr[n];
    int deg = rowptr[n + 1] - beg;
    const float4 ad = adst[wid];
    int h = lane >> 4;
    const float* zbase = z1 + t * 64 + lane;    // + src*512

    float m0 = -1e30f, m1 = -1e30f, m2 = -1e30f, m3 = -1e30f;
    float s0 = 0.f, s1 = 0.f, s2 = 0.f, s3 = 0.f;
    float acc = 0.f;
    for (int base = 0; base < deg; base += 64) {
        int rem = deg - base;
        int cn = rem < 64 ? rem : 64;
        int src = 0;
        float l0 = -1e30f, l1 = -1e30f, l2 = -1e30f, l3 = -1e30f;
        if (lane < cn) {
            src = colsrc[beg + base + lane];
            const float4 as = asrc[src * 8 + t];
            l0 = lrelu(as.x + ad.x);
            l1 = lrelu(as.y + ad.y);
            l2 = lrelu(as.z + ad.z);
            l3 = lrelu(as.w + ad.w);
        }
        float nm0 = fmaxf(m0, wmaxf(l0)), nm1 = fmaxf(m1, wmaxf(l1));
        float nm2 = fmaxf(m2, wmaxf(l2)), nm3 = fmaxf(m3, wmaxf(l3));
        float f0 = expf(m0 - nm0), f1 = expf(m1 - nm1), f2 = expf(m2 - nm2), f3 = expf(m3 - nm3);
        float w0 = (lane < cn) ? expf(l0 - nm0) : 0.f;
        float w1 = (lane < cn) ? expf(l1 - nm1) : 0.f;
        float w2 = (lane < cn) ? expf(l2 - nm2) : 0.f;
        float w3 = (lane < cn) ? expf(l3 - nm3) : 0.f;
        s0 = s0 * f0 + wsumf(w0);
        s1 = s1 * f1 + wsumf(w1);
        s2 = s2 * f2 + wsumf(w2);
        s3 = s3 * f3 + wsumf(w3);
        acc *= (h == 0) ? f0 : (h == 1) ? f1 : (h == 2) ? f2 : f3;
        m0 = nm0; m1 = nm1; m2 = nm2; m3 = nm3;
        sSrc[wslot][lane] = src;
        sWgt[wslot][lane] = make_float4(w0, w1, w2, w3);
#pragma unroll 4
        for (int e = 0; e < cn; ++e) {
            int se = sSrc[wslot][e];
            float we = ((const float*)&sWgt[wslot][e])[h];
            acc += we * zbase[se * 512];
        }
    }
    float sh = (h == 0) ? s0 : (h == 1) ? s1 : (h == 2) ? s2 : s3;
    float o = eluf(acc / sh + b1[lane]);

    // fused layer-2 projection: row o (64 ch) -> z2 (32 ch) + attention logits
    sRow[wslot][lane] = o;
    int k = lane & 31, half = lane >> 5;
    float zk = 0.f;
#pragma unroll
    for (int j = 0; j < 32; ++j)
        zk += sRow[wslot][half * 32 + j] * sW2[(half * 32 + j) * 32 + k];
    zk += __shfl_xor(zk, 32);
    float pa = zk * sAs2[k];
    float pd = zk * sAd2[k];
#pragma unroll
    for (int o2 = 1; o2 < 32; o2 <<= 1) { pa += __shfl_xor(pa, o2); pd += __shfl_xor(pd, o2); }
    if (lane < 32) z2[(size_t)wid * 32 + k] = zk;
    if (lane == 0) { asrc2[wid] = pa; adst2[wid] = pd; }
}

// ---------------- layer 2 gather + fused node-mean partials ----------------
__global__ void __launch_bounds__(256) k_l2_gather(
        const int* __restrict__ rowptr, const int* __restrict__ colsrc,
        const float* __restrict__ asrc, const float* __restrict__ adst,
        const float* __restrict__ z2, const float* __restrict__ b2,
        float* __restrict__ curh) {
    __shared__ int sSrc[4][64];
    __shared__ float sWgt[4][64];
    __shared__ float sAcc[4][32];
    int tid = threadIdx.x;
    int lane = tid & 63;
    int wslot = tid >> 6;
    int wid = blockIdx.x * 4 + wslot;  // n*8+t
    int n = wid >> 3, t = wid & 7;
    int beg = rowptr[n];
    int deg = rowptr[n + 1] - beg;
    float ad = adst[wid];
    int c = lane & 31, sub = lane >> 5;
    const float* zbase = z2 + t * 32 + c;  // + src*256
    float m = -1e30f, s = 0.f, acc = 0.f;
    for (int base = 0; base < deg; base += 64) {
        int rem = deg - base;
        int cn = rem < 64 ? rem : 64;
        int src = 0;
        float lg = -1e30f;
        if (lane < cn) {
            src = colsrc[beg + base + lane];
            lg = lrelu(asrc[src * 8 + t] + ad);
        }
        float nm = fmaxf(m, wmaxf(lg));
        float f = expf(m - nm);
        float w = (lane < cn) ? expf(lg - nm) : 0.f;
        s = s * f + wsumf(w);
        acc *= f;
        m = nm;
        sSrc[wslot][lane] = src;
        sWgt[wslot][lane] = w;
#pragma unroll 4
        for (int e = 0; e < cn; e += 2) {
            int ee = e + sub;
            if (ee < cn) acc += sWgt[wslot][ee] * zbase[sSrc[wslot][ee] * 256];
        }
    }
    acc += __shfl_xor(acc, 32);
    float val = eluf(acc / s + b2[c]);
    if (lane < 32) sAcc[wslot][c] = val;
    __syncthreads();
    if (tid < 128) {
        int slot = tid >> 5, cc = tid & 31;
        int ts = (blockIdx.x * 4 + slot) & 7;
        atomicAdd(&curh[ts * 32 + cc], sAcc[slot][cc]);
    }
}

// ---------------- GRU + heads + SIR rollout (single block, 128 threads) ----------------
__global__ void k_head(const float* __restrict__ cur_h, const float* __restrict__ h0,
                       const float* __restrict__ W_ih, const float* __restrict__ W_hh,
                       const float* __restrict__ b_ih, const float* __restrict__ b_hh,
                       const float* __restrict__ Wi, const float* __restrict__ bi,
                       const float* __restrict__ Wr, const float* __restrict__ br,
                       const float* __restrict__ Ws, const float* __restrict__ bs,
                       const float* __restrict__ cI, const float* __restrict__ cR,
                       const float* __restrict__ Nptr, const float* __restrict__ Ivec,
                       const float* __restrict__ Rvec, float* __restrict__ out) {
    __shared__ float h[32], gi[96], gh[96], hnew[32], hs[T_STEPS * 32], sirv[16];
    const float invN = 1.0f / (float)N_NODES;
    int j = threadIdx.x;
    if (j < 32) h[j] = h0[j];
    __syncthreads();
    for (int t = 0; t < T_STEPS; ++t) {
        if (j < 96) {
            float accI = b_ih[j], accH = b_hh[j];
            const float* xt = cur_h + t * 32;
            for (int k = 0; k < 32; ++k) {
                accI += W_ih[j * 32 + k] * (xt[k] * invN);
                accH += W_hh[j * 32 + k] * h[k];
            }
            gi[j] = accI;
            gh[j] = accH;
        }
        __syncthreads();
        if (j < 32) {
            float r = sigmoidf(gi[j] + gh[j]);
            float zg = sigmoidf(gi[32 + j] + gh[32 + j]);
            float ng = tanhf(gi[64 + j] + r * gh[64 + j]);
            hnew[j] = (1.f - zg) * ng + zg * h[j];
        }
        __syncthreads();
        if (j < 32) {
            h[j] = hnew[j];
            hs[t * 32 + j] = hnew[j];
        }
        __syncthreads();
    }
    if (j < 32) out[512 + j] = h[j];  // h_final
    {
        int t = j >> 4, p = j & 15;
        float accI = bi[p], accR = br[p];
        for (int k = 0; k < 34; ++k) {
            float hck = (k < 32) ? hs[t * 32 + k] : (k == 32 ? cI[t] : cR[t]);
            accI += hck * Wi[p * 34 + k];
            accR += hck * Wr[p * 34 + k];
        }
        out[j] = accI;
        out[128 + j] = accR;
    }
    if (j < 16) {
        int t = j >> 1, q = j & 1;
        float acc = bs[q];
        for (int k = 0; k < 34; ++k) {
            float hck = (k < 32) ? hs[t * 32 + k] : (k == 32 ? cI[t] : cR[t]);
            acc += hck * Ws[q * 34 + k];
        }
        sirv[j] = acc;
    }
    __syncthreads();
    if (j < 8) {
        int t = j;
        float alpha = sigmoidf(sirv[2 * t]);
        float beta = sigmoidf(sirv[2 * t + 1]);
        float Np = Nptr[0];
        float lI = Ivec[t], lR = Rvec[t];
        for (int p = 0; p < PW; ++p) {
            float lS = Np - lI - lR;
            float dI = alpha * lI * (lS / Np) - beta * lI;
            float dR = beta * lI;
            out[256 + t * 16 + p] = dI;
            out[384 + t * 16 + p] = dR;
            lI += dI;
            lR += dR;
        }
    }
}

extern "C" void kernel_launch(void* const* d_in, const int* in_sizes, int n_in,
                              void* d_out, int out_size, void* d_ws, size_t ws_size,
                              hipStream_t stream) {
    const float* dyn = (const float*)d_in[0];
    const float* cI = (const float*)d_in[1];
    const float* cR = (const float*)d_in[2];
    const float* Nptr = (const float*)d_in[3];
    const float* Ivec = (const float*)d_in[4];
    const float* Rvec = (const float*)d_in[5];
    const int* ei = (const int*)d_in[6];
    const float* h0 = (const float*)d_in[7];
    const float* W1 = (const float*)d_in[8];
    const float* as1 = (const float*)d_in[9];
    const float* ad1 = (const float*)d_in[10];
    const float* b1 = (const float*)d_in[11];
    const float* W2 = (const float*)d_in[12];
    const float* as2 = (const float*)d_in[13];
    const float* ad2 = (const float*)d_in[14];
    const float* b2 = (const float*)d_in[15];
    const float* W_ih = (const float*)d_in[16];
    const float* W_hh = (const float*)d_in[17];
    const float* b_ih = (const float*)d_in[18];
    const float* b_hh = (const float*)d_in[19];
    const float* Wi = (const float*)d_in[20];
    const float* bi = (const float*)d_in[21];
    const float* Wr = (const float*)d_in[22];
    const float* br = (const float*)d_in[23];
    const float* Ws = (const float*)d_in[24];
    const float* bs = (const float*)d_in[25];
    float* out = (float*)d_out;

    char* ws = (char*)d_ws;
    size_t off = 0;
    auto alloc = [&](size_t bytes) {
        void* p = ws + off;
        off += (bytes + 255) & ~(size_t)255;
        return p;
    };
    const size_t TN = (size_t)T_STEPS * N_NODES;
    float* z1 = (float*)alloc(TN * 64 * 4);
    float4* asrc1 = (float4*)alloc(TN * 4 * 4);
    float4* adst1 = (float4*)alloc(TN * 4 * 4);
    float* z2 = (float*)alloc(TN * 32 * 4);
    float* asrc2 = (float*)alloc(TN * 4);
    float* adst2 = (float*)alloc(TN * 4);
    float* curh = (float*)alloc(T_STEPS * 32 * 4);
    int* cnt = (int*)alloc((N_NODES + 1) * 4);
    int* rowptr = (int*)alloc((N_NODES + 1) * 4);
    int* cursor = (int*)alloc(N_NODES * 4);
    int* colsrc = (int*)alloc((size_t)ETOT * 4);
    (void)ws_size; (void)in_sizes; (void)n_in; (void)out_size;

    const int BT = 256;
    hipMemsetAsync(cnt, 0, (N_NODES + 1) * 4, stream);
    hipMemsetAsync(curh, 0, T_STEPS * 32 * 4, stream);
    int gEdgeFlat = (ETOT + BT - 1) / BT;
    k_count<<<gEdgeFlat, BT, 0, stream>>>(ei, cnt);
    k_scan<<<1, 256, 0, stream>>>(cnt, rowptr, cursor);
    k_scatter<<<gEdgeFlat, BT, 0, stream>>>(ei, cursor, colsrc);

    int gNode = (int)((TN + BT - 1) / BT);  // 313
    int gWave = (int)(TN / 4);              // 20000 blocks, 4 waves each — exact

    k_l1_proj<<<gNode, BT, 0, stream>>>(dyn, W1, as1, ad1, z1, asrc1, adst1);
    k_l1_gather<<<gWave, BT, 0, stream>>>(rowptr, colsrc, asrc1, adst1, z1, b1,
                                          W2, as2, ad2, z2, asrc2, adst2);
    k_l2_gather<<<gWave, BT, 0, stream>>>(rowptr, colsrc, asrc2, adst2, z2, b2, curh);
    k_head<<<1, 128, 0, stream>>>(curh, h0, W_ih, W_hh, b_ih, b_hh, Wi, bi, Wr, br, Ws, bs,
                                  cI, cR, Nptr, Ivec, Rvec, out);
}

// Round 4
// 348.800 us; speedup vs baseline: 1.5475x; 1.5475x over previous
//
#include <hip/hip_runtime.h>

// ---------------- problem constants ----------------
#define N_NODES 10000
#define T_STEPS 8
#define F_IN 4
#define H1 16
#define HEADS 4
#define H2 32
#define G 32
#define PW 16
#define E_EDGES 160000
#define ETOT (E_EDGES + N_NODES)   // edges + self loops = 170000
#define NREP 128                   // curh atomic replicas

__device__ __forceinline__ float lrelu(float x) { return x > 0.f ? x : 0.2f * x; }
__device__ __forceinline__ float eluf(float x) { return x > 0.f ? x : (expf(x) - 1.f); }
__device__ __forceinline__ float sigmoidf(float x) { return 1.f / (1.f + expf(-x)); }
__device__ __forceinline__ float wmaxf(float v) {
#pragma unroll
    for (int o = 32; o; o >>= 1) v = fmaxf(v, __shfl_xor(v, o));
    return v;
}
__device__ __forceinline__ float wsumf(float v) {
#pragma unroll
    for (int o = 32; o; o >>= 1) v += __shfl_xor(v, o);
    return v;
}
// bf16 <-> fp32 (payload compression for gathers)
__device__ __forceinline__ float bf2f(unsigned short u) {
    return __uint_as_float(((unsigned)u) << 16);
}
__device__ __forceinline__ unsigned short f2bf(float f) {
    unsigned b = __float_as_uint(f);
    return (unsigned short)((b + 0x7FFFu + ((b >> 16) & 1u)) >> 16);
}

// ---------------- CSR build (counting sort by dst) ----------------
__global__ void k_count(const int* __restrict__ ei, int* __restrict__ cnt) {
    int idx = blockIdx.x * blockDim.x + threadIdx.x;
    if (idx >= ETOT) return;
    int dst = (idx < E_EDGES) ? ei[E_EDGES + idx] : (idx - E_EDGES);
    atomicAdd(&cnt[dst], 1);
}

__global__ void k_scan(const int* __restrict__ cnt, int* __restrict__ rowptr,
                       int* __restrict__ cursor) {
    __shared__ int ssum[256];
    const int CH = (N_NODES + 255) / 256;  // 40
    int tid = threadIdx.x;
    int base = tid * CH;
    int loc = 0;
    for (int i = 0; i < CH; ++i) {
        int idx = base + i;
        if (idx < N_NODES) loc += cnt[idx];
    }
    ssum[tid] = loc;
    __syncthreads();
    for (int st = 1; st < 256; st <<= 1) {
        int v = (tid >= st) ? ssum[tid - st] : 0;
        __syncthreads();
        ssum[tid] += v;
        __syncthreads();
    }
    int run = ssum[tid] - loc;  // exclusive
    for (int i = 0; i < CH; ++i) {
        int idx = base + i;
        if (idx < N_NODES) {
            rowptr[idx] = run;
            cursor[idx] = run;
            run += cnt[idx];
        }
    }
    if (tid == 255) rowptr[N_NODES] = ssum[255];
}

__global__ void k_scatter(const int* __restrict__ ei, int* __restrict__ cursor,
                          int* __restrict__ colsrc) {
    int idx = blockIdx.x * blockDim.x + threadIdx.x;
    if (idx >= ETOT) return;
    int src = (idx < E_EDGES) ? ei[idx] : (idx - E_EDGES);
    int dst = (idx < E_EDGES) ? ei[E_EDGES + idx] : (idx - E_EDGES);
    int pos = atomicAdd(&cursor[dst], 1);
    colsrc[pos] = src;
}

// ---------------- layer 1: projection + attention logits ----------------
// z1 bf16 [(n*8+t)*64]; asrc1/adst1 float4 at (n*8+t)
__global__ void __launch_bounds__(256) k_l1_proj(
        const float* __restrict__ dyn, const float* __restrict__ W1,
        const float* __restrict__ as1, const float* __restrict__ ad1,
        unsigned short* __restrict__ z1, float4* __restrict__ asrc,
        float4* __restrict__ adst) {
    __shared__ float sW[256], sAs[64], sAd[64];
    int tid = threadIdx.x;
    if (tid < 256) sW[tid] = W1[tid];
    if (tid < 64) { sAs[tid] = as1[tid]; sAd[tid] = ad1[tid]; }
    __syncthreads();
    int idx = blockIdx.x * blockDim.x + tid;  // idx = n*8+t  (dyn is [n][t][4])
    if (idx >= T_STEPS * N_NODES) return;
    const float4 xv = *reinterpret_cast<const float4*>(dyn + (size_t)idx * F_IN);
    unsigned int* zrow32 = reinterpret_cast<unsigned int*>(z1 + (size_t)idx * 64);
    float a_s[HEADS] = {0.f, 0.f, 0.f, 0.f};
    float a_d[HEADS] = {0.f, 0.f, 0.f, 0.f};
    unsigned int packlo = 0;
#pragma unroll
    for (int j = 0; j < 64; ++j) {
        float z = xv.x * sW[j] + xv.y * sW[64 + j] + xv.z * sW[128 + j] + xv.w * sW[192 + j];
        if ((j & 1) == 0) packlo = f2bf(z);
        else zrow32[j >> 1] = packlo | ((unsigned)f2bf(z) << 16);
        int h = j >> 4;
        a_s[h] += z * sAs[j];
        a_d[h] += z * sAd[j];
    }
    asrc[idx] = make_float4(a_s[0], a_s[1], a_s[2], a_s[3]);
    adst[idx] = make_float4(a_d[0], a_d[1], a_d[2], a_d[3]);
}

// ---------------- layer 1 gather + fused layer-2 projection ----------------
// one wave per (n,t); 4 waves/block share n. Writes z2 bf16, asrc2/adst2 fp32.
__global__ void __launch_bounds__(256) k_l1_gather(
        const int* __restrict__ rowptr, const int* __restrict__ colsrc,
        const float4* __restrict__ asrc, const float4* __restrict__ adst,
        const unsigned short* __restrict__ z1, const float* __restrict__ b1,
        const float* __restrict__ W2, const float* __restrict__ as2,
        const float* __restrict__ ad2, unsigned short* __restrict__ z2,
        float* __restrict__ asrc2, float* __restrict__ adst2) {
    __shared__ int sSrc[4][64];
    __shared__ float4 sWgt[4][64];
    __shared__ float sRow[4][64];
    __shared__ float sW2[64 * 32];
    __shared__ float sAs2[32], sAd2[32];
    int tid = threadIdx.x;
    for (int i = tid; i < 64 * 32; i += 256) sW2[i] = W2[i];
    if (tid < 32) { sAs2[tid] = as2[tid]; sAd2[tid] = ad2[tid]; }
    __syncthreads();

    int lane = tid & 63;
    int wslot = tid >> 6;
    int wid = blockIdx.x * 4 + wslot;           // == n*8+t
    int n = wid >> 3, t = wid & 7;
    int beg = rowptr[n];
    int deg = rowptr[n + 1] - beg;
    const float4 ad = adst[wid];
    int h = lane >> 4;
    const unsigned short* zbase = z1 + t * 64 + lane;  // + src*512

    float m0 = -1e30f, m1 = -1e30f, m2 = -1e30f, m3 = -1e30f;
    float s0 = 0.f, s1 = 0.f, s2 = 0.f, s3 = 0.f;
    float acc = 0.f;
    for (int base = 0; base < deg; base += 64) {
        int rem = deg - base;
        int cn = rem < 64 ? rem : 64;
        int src = 0;
        float l0 = -1e30f, l1 = -1e30f, l2 = -1e30f, l3 = -1e30f;
        if (lane < cn) {
            src = colsrc[beg + base + lane];
            const float4 as = asrc[src * 8 + t];
            l0 = lrelu(as.x + ad.x);
            l1 = lrelu(as.y + ad.y);
            l2 = lrelu(as.z + ad.z);
            l3 = lrelu(as.w + ad.w);
        }
        float nm0 = fmaxf(m0, wmaxf(l0)), nm1 = fmaxf(m1, wmaxf(l1));
        float nm2 = fmaxf(m2, wmaxf(l2)), nm3 = fmaxf(m3, wmaxf(l3));
        float f0 = expf(m0 - nm0), f1 = expf(m1 - nm1), f2 = expf(m2 - nm2), f3 = expf(m3 - nm3);
        float w0 = (lane < cn) ? expf(l0 - nm0) : 0.f;
        float w1 = (lane < cn) ? expf(l1 - nm1) : 0.f;
        float w2 = (lane < cn) ? expf(l2 - nm2) : 0.f;
        float w3 = (lane < cn) ? expf(l3 - nm3) : 0.f;
        s0 = s0 * f0 + wsumf(w0);
        s1 = s1 * f1 + wsumf(w1);
        s2 = s2 * f2 + wsumf(w2);
        s3 = s3 * f3 + wsumf(w3);
        acc *= (h == 0) ? f0 : (h == 1) ? f1 : (h == 2) ? f2 : f3;
        m0 = nm0; m1 = nm1; m2 = nm2; m3 = nm3;
        sSrc[wslot][lane] = src;
        sWgt[wslot][lane] = make_float4(w0, w1, w2, w3);
#pragma unroll 4
        for (int e = 0; e < cn; ++e) {
            int se = sSrc[wslot][e];
            float we = ((const float*)&sWgt[wslot][e])[h];
            acc += we * bf2f(zbase[se * 512]);
        }
    }
    float sh = (h == 0) ? s0 : (h == 1) ? s1 : (h == 2) ? s2 : s3;
    float o = eluf(acc / sh + b1[lane]);

    // fused layer-2 projection: row o (64 ch) -> z2 (32 ch) + attention logits
    sRow[wslot][lane] = o;
    int k = lane & 31, half = lane >> 5;
    float zk = 0.f;
#pragma unroll
    for (int j = 0; j < 32; ++j)
        zk += sRow[wslot][half * 32 + j] * sW2[(half * 32 + j) * 32 + k];
    zk += __shfl_xor(zk, 32);
    float pa = zk * sAs2[k];
    float pd = zk * sAd2[k];
#pragma unroll
    for (int o2 = 1; o2 < 32; o2 <<= 1) { pa += __shfl_xor(pa, o2); pd += __shfl_xor(pd, o2); }
    if (lane < 32) z2[(size_t)wid * 32 + k] = f2bf(zk);
    if (lane == 0) { asrc2[wid] = pa; adst2[wid] = pd; }
}

// ---------------- layer 2 gather + spread-replica node-mean ----------------
__global__ void __launch_bounds__(256) k_l2_gather(
        const int* __restrict__ rowptr, const int* __restrict__ colsrc,
        const float* __restrict__ asrc, const float* __restrict__ adst,
        const unsigned short* __restrict__ z2, const float* __restrict__ b2,
        float* __restrict__ part) {
    __shared__ int sSrc[4][64];
    __shared__ float sWgt[4][64];
    int tid = threadIdx.x;
    int lane = tid & 63;
    int wslot = tid >> 6;
    int wid = blockIdx.x * 4 + wslot;  // n*8+t
    int n = wid >> 3, t = wid & 7;
    int beg = rowptr[n];
    int deg = rowptr[n + 1] - beg;
    float ad = adst[wid];
    int c = lane & 31, sub = lane >> 5;
    const unsigned short* zbase = z2 + t * 32 + c;  // + src*256
    float m = -1e30f, s = 0.f, acc = 0.f;
    for (int base = 0; base < deg; base += 64) {
        int rem = deg - base;
        int cn = rem < 64 ? rem : 64;
        int src = 0;
        float lg = -1e30f;
        if (lane < cn) {
            src = colsrc[beg + base + lane];
            lg = lrelu(asrc[src * 8 + t] + ad);
        }
        float nm = fmaxf(m, wmaxf(lg));
        float f = expf(m - nm);
        float w = (lane < cn) ? expf(lg - nm) : 0.f;
        s = s * f + wsumf(w);
        acc *= f;
        m = nm;
        sSrc[wslot][lane] = src;
        sWgt[wslot][lane] = w;
#pragma unroll 4
        for (int e = 0; e < cn; e += 2) {
            int ee = e + sub;
            if (ee < cn) acc += sWgt[wslot][ee] * bf2f(zbase[sSrc[wslot][ee] * 256]);
        }
    }
    acc += __shfl_xor(acc, 32);
    if (lane < 32) {
        float val = eluf(acc / s + b2[c]);
        atomicAdd(&part[((blockIdx.x & (NREP - 1)) << 8) + t * 32 + c], val);
    }
}

// ---------------- replica-reduce + GRU + heads + SIR (single block, 128 thr) ----------------
__global__ void k_head(const float* __restrict__ part, const float* __restrict__ h0,
                       const float* __restrict__ W_ih, const float* __restrict__ W_hh,
                       const float* __restrict__ b_ih, const float* __restrict__ b_hh,
                       const float* __restrict__ Wi, const float* __restrict__ bi,
                       const float* __restrict__ Wr, const float* __restrict__ br,
                       const float* __restrict__ Ws, const float* __restrict__ bs,
                       const float* __restrict__ cI, const float* __restrict__ cR,
                       const float* __restrict__ Nptr, const float* __restrict__ Ivec,
                       const float* __restrict__ Rvec, float* __restrict__ out) {
    __shared__ float xs[256];  // cur_h [8][32]
    __shared__ float h[32], gi[96], gh[96], hnew[32], hs[T_STEPS * 32], sirv[16];
    const float invN = 1.0f / (float)N_NODES;
    int j = threadIdx.x;
    // reduce NREP replicas
#pragma unroll
    for (int p = 0; p < 2; ++p) {
        int e = j + p * 128;
        float sum = 0.f;
        for (int r = 0; r < NREP; ++r) sum += part[r * 256 + e];
        xs[e] = sum * invN;
    }
    if (j < 32) h[j] = h0[j];
    __syncthreads();
    for (int t = 0; t < T_STEPS; ++t) {
        if (j < 96) {
            float accI = b_ih[j], accH = b_hh[j];
            for (int k = 0; k < 32; ++k) {
                accI += W_ih[j * 32 + k] * xs[t * 32 + k];
                accH += W_hh[j * 32 + k] * h[k];
            }
            gi[j] = accI;
            gh[j] = accH;
        }
        __syncthreads();
        if (j < 32) {
            float r = sigmoidf(gi[j] + gh[j]);
            float zg = sigmoidf(gi[32 + j] + gh[32 + j]);
            float ng = tanhf(gi[64 + j] + r * gh[64 + j]);
            hnew[j] = (1.f - zg) * ng + zg * h[j];
        }
        __syncthreads();
        if (j < 32) {
            h[j] = hnew[j];
            hs[t * 32 + j] = hnew[j];
        }
        __syncthreads();
    }
    if (j < 32) out[512 + j] = h[j];  // h_final
    {
        int t = j >> 4, p = j & 15;
        float accI = bi[p], accR = br[p];
        for (int k = 0; k < 34; ++k) {
            float hck = (k < 32) ? hs[t * 32 + k] : (k == 32 ? cI[t] : cR[t]);
            accI += hck * Wi[p * 34 + k];
            accR += hck * Wr[p * 34 + k];
        }
        out[j] = accI;
        out[128 + j] = accR;
    }
    if (j < 16) {
        int t = j >> 1, q = j & 1;
        float acc = bs[q];
        for (int k = 0; k < 34; ++k) {
            float hck = (k < 32) ? hs[t * 32 + k] : (k == 32 ? cI[t] : cR[t]);
            acc += hck * Ws[q * 34 + k];
        }
        sirv[j] = acc;
    }
    __syncthreads();
    if (j < 8) {
        int t = j;
        float alpha = sigmoidf(sirv[2 * t]);
        float beta = sigmoidf(sirv[2 * t + 1]);
        float Np = Nptr[0];
        float lI = Ivec[t], lR = Rvec[t];
        for (int p = 0; p < PW; ++p) {
            float lS = Np - lI - lR;
            float dI = alpha * lI * (lS / Np) - beta * lI;
            float dR = beta * lI;
            out[256 + t * 16 + p] = dI;
            out[384 + t * 16 + p] = dR;
            lI += dI;
            lR += dR;
        }
    }
}

extern "C" void kernel_launch(void* const* d_in, const int* in_sizes, int n_in,
                              void* d_out, int out_size, void* d_ws, size_t ws_size,
                              hipStream_t stream) {
    const float* dyn = (const float*)d_in[0];
    const float* cI = (const float*)d_in[1];
    const float* cR = (const float*)d_in[2];
    const float* Nptr = (const float*)d_in[3];
    const float* Ivec = (const float*)d_in[4];
    const float* Rvec = (const float*)d_in[5];
    const int* ei = (const int*)d_in[6];
    const float* h0 = (const float*)d_in[7];
    const float* W1 = (const float*)d_in[8];
    const float* as1 = (const float*)d_in[9];
    const float* ad1 = (const float*)d_in[10];
    const float* b1 = (const float*)d_in[11];
    const float* W2 = (const float*)d_in[12];
    const float* as2 = (const float*)d_in[13];
    const float* ad2 = (const float*)d_in[14];
    const float* b2 = (const float*)d_in[15];
    const float* W_ih = (const float*)d_in[16];
    const float* W_hh = (const float*)d_in[17];
    const float* b_ih = (const float*)d_in[18];
    const float* b_hh = (const float*)d_in[19];
    const float* Wi = (const float*)d_in[20];
    const float* bi = (const float*)d_in[21];
    const float* Wr = (const float*)d_in[22];
    const float* br = (const float*)d_in[23];
    const float* Ws = (const float*)d_in[24];
    const float* bs = (const float*)d_in[25];
    float* out = (float*)d_out;

    char* ws = (char*)d_ws;
    size_t off = 0;
    auto alloc = [&](size_t bytes) {
        void* p = ws + off;
        off += (bytes + 255) & ~(size_t)255;
        return p;
    };
    const size_t TN = (size_t)T_STEPS * N_NODES;
    unsigned short* z1 = (unsigned short*)alloc(TN * 64 * 2);
    float4* asrc1 = (float4*)alloc(TN * 16);
    float4* adst1 = (float4*)alloc(TN * 16);
    unsigned short* z2 = (unsigned short*)alloc(TN * 32 * 2);
    float* asrc2 = (float*)alloc(TN * 4);
    float* adst2 = (float*)alloc(TN * 4);
    float* part = (float*)alloc((size_t)NREP * 256 * 4);
    int* cnt = (int*)alloc((N_NODES + 1) * 4);
    int* rowptr = (int*)alloc((N_NODES + 1) * 4);
    int* cursor = (int*)alloc(N_NODES * 4);
    int* colsrc = (int*)alloc((size_t)ETOT * 4);
    (void)ws_size; (void)in_sizes; (void)n_in; (void)out_size;

    const int BT = 256;
    hipMemsetAsync(cnt, 0, (N_NODES + 1) * 4, stream);
    hipMemsetAsync(part, 0, (size_t)NREP * 256 * 4, stream);
    int gEdgeFlat = (ETOT + BT - 1) / BT;
    k_count<<<gEdgeFlat, BT, 0, stream>>>(ei, cnt);
    k_scan<<<1, 256, 0, stream>>>(cnt, rowptr, cursor);
    k_scatter<<<gEdgeFlat, BT, 0, stream>>>(ei, cursor, colsrc);

    int gNode = (int)((TN + BT - 1) / BT);  // 313
    int gWave = (int)(TN / 4);              // 20000 blocks, 4 waves each — exact

    k_l1_proj<<<gNode, BT, 0, stream>>>(dyn, W1, as1, ad1, z1, asrc1, adst1);
    k_l1_gather<<<gWave, BT, 0, stream>>>(rowptr, colsrc, asrc1, adst1, z1, b1,
                                          W2, as2, ad2, z2, asrc2, adst2);
    k_l2_gather<<<gWave, BT, 0, stream>>>(rowptr, colsrc, asrc2, adst2, z2, b2, part);
    k_head<<<1, 128, 0, stream>>>(part, h0, W_ih, W_hh, b_ih, b_hh, Wi, bi, Wr, br, Ws, bs,
                                  cI, cR, Nptr, Ivec, Rvec, out);
}

// Round 5
// 251.965 us; speedup vs baseline: 2.1422x; 1.3843x over previous
//
#include <hip/hip_runtime.h>

// ---------------- problem constants ----------------
#define N_NODES 10000
#define T_STEPS 8
#define F_IN 4
#define H1 16
#define HEADS 4
#define H2 32
#define G 32
#define PW 16
#define E_EDGES 160000
#define ETOT (E_EDGES + N_NODES)   // edges + self loops = 170000
#define NREP 128                   // curh atomic replicas

__device__ __forceinline__ float lrelu(float x) { return x > 0.f ? x : 0.2f * x; }
__device__ __forceinline__ float eluf(float x) { return x > 0.f ? x : (expf(x) - 1.f); }
__device__ __forceinline__ float sigmoidf(float x) { return 1.f / (1.f + expf(-x)); }
__device__ __forceinline__ float wmaxf(float v) {
#pragma unroll
    for (int o = 32; o; o >>= 1) v = fmaxf(v, __shfl_xor(v, o));
    return v;
}
__device__ __forceinline__ float wsumf(float v) {
#pragma unroll
    for (int o = 32; o; o >>= 1) v += __shfl_xor(v, o);
    return v;
}
// reductions over the 8 lanes sharing the same t (lane = es*8 + t)
__device__ __forceinline__ float g8max(float v) {
    v = fmaxf(v, __shfl_xor(v, 8));
    v = fmaxf(v, __shfl_xor(v, 16));
    v = fmaxf(v, __shfl_xor(v, 32));
    return v;
}
__device__ __forceinline__ float g8sum(float v) {
    v += __shfl_xor(v, 8);
    v += __shfl_xor(v, 16);
    v += __shfl_xor(v, 32);
    return v;
}
// bf16 <-> fp32
__device__ __forceinline__ float bf2f(unsigned short u) {
    return __uint_as_float(((unsigned)u) << 16);
}
__device__ __forceinline__ unsigned short f2bf(float f) {
    unsigned b = __float_as_uint(f);
    return (unsigned short)((b + 0x7FFFu + ((b >> 16) & 1u)) >> 16);
}

// ---------------- CSR build (counting sort by dst) ----------------
__global__ void k_count(const int* __restrict__ ei, int* __restrict__ cnt) {
    int idx = blockIdx.x * blockDim.x + threadIdx.x;
    if (idx >= ETOT) return;
    int dst = (idx < E_EDGES) ? ei[E_EDGES + idx] : (idx - E_EDGES);
    atomicAdd(&cnt[dst], 1);
}

__global__ void k_scan(const int* __restrict__ cnt, int* __restrict__ rowptr,
                       int* __restrict__ cursor) {
    __shared__ int ssum[256];
    const int CH = (N_NODES + 255) / 256;  // 40
    int tid = threadIdx.x;
    int base = tid * CH;
    int loc = 0;
    for (int i = 0; i < CH; ++i) {
        int idx = base + i;
        if (idx < N_NODES) loc += cnt[idx];
    }
    ssum[tid] = loc;
    __syncthreads();
    for (int st = 1; st < 256; st <<= 1) {
        int v = (tid >= st) ? ssum[tid - st] : 0;
        __syncthreads();
        ssum[tid] += v;
        __syncthreads();
    }
    int run = ssum[tid] - loc;  // exclusive
    for (int i = 0; i < CH; ++i) {
        int idx = base + i;
        if (idx < N_NODES) {
            rowptr[idx] = run;
            cursor[idx] = run;
            run += cnt[idx];
        }
    }
    if (tid == 255) rowptr[N_NODES] = ssum[255];
}

__global__ void k_scatter(const int* __restrict__ ei, int* __restrict__ cursor,
                          int* __restrict__ colsrc) {
    int idx = blockIdx.x * blockDim.x + threadIdx.x;
    if (idx >= ETOT) return;
    int src = (idx < E_EDGES) ? ei[idx] : (idx - E_EDGES);
    int dst = (idx < E_EDGES) ? ei[E_EDGES + idx] : (idx - E_EDGES);
    int pos = atomicAdd(&cursor[dst], 1);
    colsrc[pos] = src;
}

// ---------------- L1 attention logits (W1 folded into a_src/a_dst) ----------------
// asrc[n*8+t] = x · (W1 @ a_src_h)  — z1 never materialized.
__global__ void __launch_bounds__(256) k_l1_att(
        const float4* __restrict__ dyn, const float* __restrict__ W1,
        const float* __restrict__ as1, const float* __restrict__ ad1,
        float4* __restrict__ asrc, float4* __restrict__ adst) {
    __shared__ float VA[16], VD[16];  // [d][h]
    int tid = threadIdx.x;
    if (tid < 32) {
        int q = tid & 15, d = q >> 2, h = q & 3;
        const float* a = (tid < 16) ? as1 : ad1;
        float acc = 0.f;
#pragma unroll
        for (int c = 0; c < 16; ++c) acc += W1[d * 64 + h * 16 + c] * a[h * 16 + c];
        if (tid < 16) VA[q] = acc;
        else VD[q] = acc;
    }
    __syncthreads();
    int idx = blockIdx.x * blockDim.x + tid;  // n*8+t
    if (idx >= T_STEPS * N_NODES) return;
    const float4 x = dyn[idx];
    float4 s4, d4;
#pragma unroll
    for (int h = 0; h < 4; ++h) {
        ((float*)&s4)[h] = x.x * VA[h] + x.y * VA[4 + h] + x.z * VA[8 + h] + x.w * VA[12 + h];
        ((float*)&d4)[h] = x.x * VD[h] + x.y * VD[4 + h] + x.z * VD[8 + h] + x.w * VD[12 + h];
    }
    asrc[idx] = s4;
    adst[idx] = d4;
}

// ---------------- L1: one wave per node, lane = es*8 + t ----------------
// u_h = sum_e w_e^h * x[src_e]  (4-dim), then out = (u_h @ W1cols)/s_h, ELU,
// fused W2 projection -> z2 (bf16), asrc2/adst2.
__global__ void __launch_bounds__(256) k_l1_node(
        const int* __restrict__ rowptr, const int* __restrict__ colsrc,
        const float4* __restrict__ asrc, const float4* __restrict__ adst,
        const float4* __restrict__ dyn, const float* __restrict__ W1,
        const float* __restrict__ b1, const float* __restrict__ W2,
        const float* __restrict__ as2, const float* __restrict__ ad2,
        unsigned short* __restrict__ z2g, float* __restrict__ asrc2,
        float* __restrict__ adst2) {
    __shared__ float sW1[256], sB1[64], sW2[64 * 32];
    __shared__ float sAs2[32], sAd2[32];
    __shared__ float sRow[4][8 * 65];
    int tid = threadIdx.x;
    for (int i = tid; i < 64 * 32; i += 256) sW2[i] = W2[i];
    if (tid < 256) sW1[tid] = W1[tid];
    if (tid < 64) sB1[tid] = b1[tid];
    if (tid < 32) { sAs2[tid] = as2[tid]; sAd2[tid] = ad2[tid]; }
    __syncthreads();

    int lane = tid & 63, wslot = tid >> 6;
    int n = blockIdx.x * 4 + wslot;
    int t = lane & 7, es = lane >> 3;
    int beg = rowptr[n];
    int deg = rowptr[n + 1] - beg;
    const float4 ad = adst[(n << 3) + t];

    float m0 = -1e30f, m1 = -1e30f, m2 = -1e30f, m3 = -1e30f;
    float s0 = 0.f, s1 = 0.f, s2 = 0.f, s3 = 0.f;
    float u[16];
#pragma unroll
    for (int i = 0; i < 16; ++i) u[i] = 0.f;

    for (int base = 0; base < deg; base += 8) {
        int e = base + es;
        bool act = e < deg;
        int src = colsrc[beg + (act ? e : 0)];
        const float4 as = asrc[(src << 3) + t];
        float l0 = act ? lrelu(as.x + ad.x) : -1e30f;
        float l1 = act ? lrelu(as.y + ad.y) : -1e30f;
        float l2 = act ? lrelu(as.z + ad.z) : -1e30f;
        float l3 = act ? lrelu(as.w + ad.w) : -1e30f;
        float nm0 = fmaxf(m0, g8max(l0)), nm1 = fmaxf(m1, g8max(l1));
        float nm2 = fmaxf(m2, g8max(l2)), nm3 = fmaxf(m3, g8max(l3));
        float f0 = expf(m0 - nm0), f1 = expf(m1 - nm1);
        float f2 = expf(m2 - nm2), f3 = expf(m3 - nm3);
        float w0 = expf(l0 - nm0), w1 = expf(l1 - nm1);
        float w2 = expf(l2 - nm2), w3 = expf(l3 - nm3);
        s0 = s0 * f0 + g8sum(w0);
        s1 = s1 * f1 + g8sum(w1);
        s2 = s2 * f2 + g8sum(w2);
        s3 = s3 * f3 + g8sum(w3);
#pragma unroll
        for (int i = 0; i < 16; ++i) {
            float f = (i < 4) ? f0 : (i < 8) ? f1 : (i < 12) ? f2 : f3;
            u[i] *= f;
        }
        const float4 x4 = dyn[(src << 3) + t];
        u[0] += w0 * x4.x; u[1] += w0 * x4.y; u[2] += w0 * x4.z; u[3] += w0 * x4.w;
        u[4] += w1 * x4.x; u[5] += w1 * x4.y; u[6] += w1 * x4.z; u[7] += w1 * x4.w;
        u[8] += w2 * x4.x; u[9] += w2 * x4.y; u[10] += w2 * x4.z; u[11] += w2 * x4.w;
        u[12] += w3 * x4.x; u[13] += w3 * x4.y; u[14] += w3 * x4.z; u[15] += w3 * x4.w;
        m0 = nm0; m1 = nm1; m2 = nm2; m3 = nm3;
    }
    // reduce u over the 8 es-lanes (per t)
#pragma unroll
    for (int i = 0; i < 16; ++i) {
        float v = u[i];
        v += __shfl_xor(v, 8);
        v += __shfl_xor(v, 16);
        v += __shfl_xor(v, 32);
        u[i] = v;
    }
    // epilogue: lane covers channels c = es*8+j  (head h = es>>1, fixed per lane)
    int h = es >> 1;
    float uh0 = (h == 0) ? u[0] : (h == 1) ? u[4] : (h == 2) ? u[8] : u[12];
    float uh1 = (h == 0) ? u[1] : (h == 1) ? u[5] : (h == 2) ? u[9] : u[13];
    float uh2 = (h == 0) ? u[2] : (h == 1) ? u[6] : (h == 2) ? u[10] : u[14];
    float uh3 = (h == 0) ? u[3] : (h == 1) ? u[7] : (h == 2) ? u[11] : u[15];
    float sh = (h == 0) ? s0 : (h == 1) ? s1 : (h == 2) ? s2 : s3;
    float inv = 1.f / sh;
#pragma unroll
    for (int j = 0; j < 8; ++j) {
        int c = es * 8 + j;
        float acc = uh0 * sW1[c] + uh1 * sW1[64 + c] + uh2 * sW1[128 + c] + uh3 * sW1[192 + c];
        sRow[wslot][t * 65 + c] = eluf(acc * inv + sB1[c]);
    }
    __syncthreads();
    // fused W2 projection: lane computes k = es*4 .. es*4+3 for its t
    float z0 = 0.f, z1v = 0.f, z2v = 0.f, z3v = 0.f;
#pragma unroll 8
    for (int j = 0; j < 64; ++j) {
        float r = sRow[wslot][t * 65 + j];
        const float4 w4 = *reinterpret_cast<const float4*>(&sW2[j * 32 + es * 4]);
        z0 += r * w4.x; z1v += r * w4.y; z2v += r * w4.z; z3v += r * w4.w;
    }
    int wid8 = (n << 3) + t;
    unsigned int p0 = (unsigned)f2bf(z0) | ((unsigned)f2bf(z1v) << 16);
    unsigned int p1 = (unsigned)f2bf(z2v) | ((unsigned)f2bf(z3v) << 16);
    uint2 pk = make_uint2(p0, p1);
    *reinterpret_cast<uint2*>(z2g + (size_t)wid8 * 32 + es * 4) = pk;
    float pa = z0 * sAs2[es * 4] + z1v * sAs2[es * 4 + 1] + z2v * sAs2[es * 4 + 2] + z3v * sAs2[es * 4 + 3];
    float pd = z0 * sAd2[es * 4] + z1v * sAd2[es * 4 + 1] + z2v * sAd2[es * 4 + 2] + z3v * sAd2[es * 4 + 3];
    pa = g8sum(pa);
    pd = g8sum(pd);
    if (es == 0) { asrc2[wid8] = pa; adst2[wid8] = pd; }
}

// ---------------- layer 2 gather + spread-replica node-mean ----------------
// one wave per (n,t); 4 edges in flight (sub = lane>>4), 2 bf16 channels/lane.
__global__ void __launch_bounds__(256) k_l2_gather(
        const int* __restrict__ rowptr, const int* __restrict__ colsrc,
        const float* __restrict__ asrc, const float* __restrict__ adst,
        const unsigned short* __restrict__ z2, const float* __restrict__ b2,
        float* __restrict__ part) {
    __shared__ int sSrc[4][64];
    __shared__ float sWgt[4][64];
    int tid = threadIdx.x;
    int lane = tid & 63;
    int wslot = tid >> 6;
    int wid = blockIdx.x * 4 + wslot;  // n*8+t
    int n = wid >> 3, t = wid & 7;
    int beg = rowptr[n];
    int deg = rowptr[n + 1] - beg;
    float ad = adst[wid];
    int c2 = (lane & 15) * 2, sub = lane >> 4;
    float m = -1e30f, s = 0.f;
    float acc0 = 0.f, acc1 = 0.f;
    for (int base = 0; base < deg; base += 64) {
        int rem = deg - base;
        int cn = rem < 64 ? rem : 64;
        int src = 0;
        float lg = -1e30f;
        if (lane < cn) {
            src = colsrc[beg + base + lane];
            lg = lrelu(asrc[src * 8 + t] + ad);
        }
        float nm = fmaxf(m, wmaxf(lg));
        float f = expf(m - nm);
        float w = (lane < cn) ? expf(lg - nm) : 0.f;
        s = s * f + wsumf(w);
        acc0 *= f;
        acc1 *= f;
        m = nm;
        sSrc[wslot][lane] = src;
        sWgt[wslot][lane] = w;
#pragma unroll 2
        for (int e0 = 0; e0 < cn; e0 += 4) {
            int ee = e0 + sub;
            float we = 0.f;
            int se = 0;
            if (ee < cn) { se = sSrc[wslot][ee]; we = sWgt[wslot][ee]; }
            unsigned int pz = *reinterpret_cast<const unsigned int*>(z2 + ((size_t)se * 8 + t) * 32 + c2);
            acc0 += we * bf2f((unsigned short)(pz & 0xFFFF));
            acc1 += we * bf2f((unsigned short)(pz >> 16));
        }
    }
    acc0 += __shfl_xor(acc0, 16); acc0 += __shfl_xor(acc0, 32);
    acc1 += __shfl_xor(acc1, 16); acc1 += __shfl_xor(acc1, 32);
    if (lane < 16) {
        float invs = 1.f / s;
        int c = lane * 2;
        float v0 = eluf(acc0 * invs + b2[c]);
        float v1 = eluf(acc1 * invs + b2[c + 1]);
        float* pb = &part[((blockIdx.x & (NREP - 1)) << 8) + t * 32 + c];
        atomicAdd(pb, v0);
        atomicAdd(pb + 1, v1);
    }
}

// ---------------- replica-reduce + GRU + heads + SIR (single block, 128 thr) ----------------
__global__ void k_head(const float* __restrict__ part, const float* __restrict__ h0,
                       const float* __restrict__ W_ih, const float* __restrict__ W_hh,
                       const float* __restrict__ b_ih, const float* __restrict__ b_hh,
                       const float* __restrict__ Wi, const float* __restrict__ bi,
                       const float* __restrict__ Wr, const float* __restrict__ br,
                       const float* __restrict__ Ws, const float* __restrict__ bs,
                       const float* __restrict__ cI, const float* __restrict__ cR,
                       const float* __restrict__ Nptr, const float* __restrict__ Ivec,
                       const float* __restrict__ Rvec, float* __restrict__ out) {
    __shared__ float xs[256];  // cur_h [8][32]
    __shared__ float h[32], gi[96], gh[96], hnew[32], hs[T_STEPS * 32], sirv[16];
    const float invN = 1.0f / (float)N_NODES;
    int j = threadIdx.x;
#pragma unroll
    for (int p = 0; p < 2; ++p) {
        int e = j + p * 128;
        float sum = 0.f;
        for (int r = 0; r < NREP; ++r) sum += part[r * 256 + e];
        xs[e] = sum * invN;
    }
    if (j < 32) h[j] = h0[j];
    __syncthreads();
    for (int t = 0; t < T_STEPS; ++t) {
        if (j < 96) {
            float accI = b_ih[j], accH = b_hh[j];
            for (int k = 0; k < 32; ++k) {
                accI += W_ih[j * 32 + k] * xs[t * 32 + k];
                accH += W_hh[j * 32 + k] * h[k];
            }
            gi[j] = accI;
            gh[j] = accH;
        }
        __syncthreads();
        if (j < 32) {
            float r = sigmoidf(gi[j] + gh[j]);
            float zg = sigmoidf(gi[32 + j] + gh[32 + j]);
            float ng = tanhf(gi[64 + j] + r * gh[64 + j]);
            hnew[j] = (1.f - zg) * ng + zg * h[j];
        }
        __syncthreads();
        if (j < 32) {
            h[j] = hnew[j];
            hs[t * 32 + j] = hnew[j];
        }
        __syncthreads();
    }
    if (j < 32) out[512 + j] = h[j];  // h_final
    {
        int t = j >> 4, p = j & 15;
        float accI = bi[p], accR = br[p];
        for (int k = 0; k < 34; ++k) {
            float hck = (k < 32) ? hs[t * 32 + k] : (k == 32 ? cI[t] : cR[t]);
            accI += hck * Wi[p * 34 + k];
            accR += hck * Wr[p * 34 + k];
        }
        out[j] = accI;
        out[128 + j] = accR;
    }
    if (j < 16) {
        int t = j >> 1, q = j & 1;
        float acc = bs[q];
        for (int k = 0; k < 34; ++k) {
            float hck = (k < 32) ? hs[t * 32 + k] : (k == 32 ? cI[t] : cR[t]);
            acc += hck * Ws[q * 34 + k];
        }
        sirv[j] = acc;
    }
    __syncthreads();
    if (j < 8) {
        int t = j;
        float alpha = sigmoidf(sirv[2 * t]);
        float beta = sigmoidf(sirv[2 * t + 1]);
        float Np = Nptr[0];
        float lI = Ivec[t], lR = Rvec[t];
        for (int p = 0; p < PW; ++p) {
            float lS = Np - lI - lR;
            float dI = alpha * lI * (lS / Np) - beta * lI;
            float dR = beta * lI;
            out[256 + t * 16 + p] = dI;
            out[384 + t * 16 + p] = dR;
            lI += dI;
            lR += dR;
        }
    }
}

extern "C" void kernel_launch(void* const* d_in, const int* in_sizes, int n_in,
                              void* d_out, int out_size, void* d_ws, size_t ws_size,
                              hipStream_t stream) {
    const float* dyn = (const float*)d_in[0];
    const float* cI = (const float*)d_in[1];
    const float* cR = (const float*)d_in[2];
    const float* Nptr = (const float*)d_in[3];
    const float* Ivec = (const float*)d_in[4];
    const float* Rvec = (const float*)d_in[5];
    const int* ei = (const int*)d_in[6];
    const float* h0 = (const float*)d_in[7];
    const float* W1 = (const float*)d_in[8];
    const float* as1 = (const float*)d_in[9];
    const float* ad1 = (const float*)d_in[10];
    const float* b1 = (const float*)d_in[11];
    const float* W2 = (const float*)d_in[12];
    const float* as2 = (const float*)d_in[13];
    const float* ad2 = (const float*)d_in[14];
    const float* b2 = (const float*)d_in[15];
    const float* W_ih = (const float*)d_in[16];
    const float* W_hh = (const float*)d_in[17];
    const float* b_ih = (const float*)d_in[18];
    const float* b_hh = (const float*)d_in[19];
    const float* Wi = (const float*)d_in[20];
    const float* bi = (const float*)d_in[21];
    const float* Wr = (const float*)d_in[22];
    const float* br = (const float*)d_in[23];
    const float* Ws = (const float*)d_in[24];
    const float* bs = (const float*)d_in[25];
    float* out = (float*)d_out;

    char* ws = (char*)d_ws;
    size_t off = 0;
    auto alloc = [&](size_t bytes) {
        void* p = ws + off;
        off += (bytes + 255) & ~(size_t)255;
        return p;
    };
    const size_t TN = (size_t)T_STEPS * N_NODES;
    float4* asrc1 = (float4*)alloc(TN * 16);
    float4* adst1 = (float4*)alloc(TN * 16);
    unsigned short* z2 = (unsigned short*)alloc(TN * 32 * 2);
    float* asrc2 = (float*)alloc(TN * 4);
    float* adst2 = (float*)alloc(TN * 4);
    float* part = (float*)alloc((size_t)NREP * 256 * 4);
    int* cnt = (int*)alloc((N_NODES + 1) * 4);
    int* rowptr = (int*)alloc((N_NODES + 1) * 4);
    int* cursor = (int*)alloc(N_NODES * 4);
    int* colsrc = (int*)alloc((size_t)ETOT * 4);
    (void)ws_size; (void)in_sizes; (void)n_in; (void)out_size;

    const int BT = 256;
    hipMemsetAsync(cnt, 0, (N_NODES + 1) * 4, stream);
    hipMemsetAsync(part, 0, (size_t)NREP * 256 * 4, stream);
    int gEdgeFlat = (ETOT + BT - 1) / BT;
    k_count<<<gEdgeFlat, BT, 0, stream>>>(ei, cnt);
    k_scan<<<1, 256, 0, stream>>>(cnt, rowptr, cursor);
    k_scatter<<<gEdgeFlat, BT, 0, stream>>>(ei, cursor, colsrc);

    int gNode = (int)((TN + BT - 1) / BT);  // 313
    k_l1_att<<<gNode, BT, 0, stream>>>((const float4*)dyn, W1, as1, ad1, asrc1, adst1);
    k_l1_node<<<N_NODES / 4, BT, 0, stream>>>(rowptr, colsrc, asrc1, adst1,
                                              (const float4*)dyn, W1, b1, W2, as2, ad2,
                                              z2, asrc2, adst2);
    k_l2_gather<<<(int)(TN / 4), BT, 0, stream>>>(rowptr, colsrc, asrc2, adst2, z2, b2, part);
    k_head<<<1, 128, 0, stream>>>(part, h0, W_ih, W_hh, b_ih, b_hh, Wi, bi, Wr, br, Ws, bs,
                                  cI, cR, Nptr, Ivec, Rvec, out);
}

// Round 6
// 212.237 us; speedup vs baseline: 2.5432x; 1.1872x over previous
//
#include <hip/hip_runtime.h>

// ---------------- problem constants ----------------
#define N_NODES 10000
#define T_STEPS 8
#define F_IN 4
#define H1 16
#define HEADS 4
#define H2 32
#define G 32
#define PW 16
#define E_EDGES 160000
#define ETOT (E_EDGES + N_NODES)   // edges + self loops = 170000
#define NREP 128                   // curh atomic replicas

__device__ __forceinline__ float lrelu(float x) { return x > 0.f ? x : 0.2f * x; }
__device__ __forceinline__ float eluf(float x) { return x > 0.f ? x : (expf(x) - 1.f); }
__device__ __forceinline__ float sigmoidf(float x) { return 1.f / (1.f + expf(-x)); }
// reductions over the 8 lanes sharing the same t (lane = es*8 + t)
__device__ __forceinline__ float g8max(float v) {
    v = fmaxf(v, __shfl_xor(v, 8));
    v = fmaxf(v, __shfl_xor(v, 16));
    v = fmaxf(v, __shfl_xor(v, 32));
    return v;
}
__device__ __forceinline__ float g8sum(float v) {
    v += __shfl_xor(v, 8);
    v += __shfl_xor(v, 16);
    v += __shfl_xor(v, 32);
    return v;
}
// bf16 <-> fp32
__device__ __forceinline__ float bf2f(unsigned int u) {
    return __uint_as_float(u << 16);
}
__device__ __forceinline__ unsigned short f2bf(float f) {
    unsigned b = __float_as_uint(f);
    return (unsigned short)((b + 0x7FFFu + ((b >> 16) & 1u)) >> 16);
}

// ---------------- fused: edge count (CSR) + L1 attention logits ----------------
// blocks [0,gEdge): count; blocks [gEdge, gEdge+gNode): asrc1/adst1 = x·(W1@a)
__global__ void __launch_bounds__(256) k_count_att(
        const int* __restrict__ ei, int* __restrict__ cnt,
        const float4* __restrict__ dyn, const float* __restrict__ W1,
        const float* __restrict__ as1, const float* __restrict__ ad1,
        float4* __restrict__ asrc, float4* __restrict__ adst, int gEdge) {
    if ((int)blockIdx.x < gEdge) {
        int idx = blockIdx.x * 256 + threadIdx.x;
        if (idx >= ETOT) return;
        int dst = (idx < E_EDGES) ? ei[E_EDGES + idx] : (idx - E_EDGES);
        atomicAdd(&cnt[dst], 1);
    } else {
        __shared__ float VA[16], VD[16];  // [d][h]
        int tid = threadIdx.x;
        if (tid < 32) {
            int q = tid & 15, d = q >> 2, h = q & 3;
            const float* a = (tid < 16) ? as1 : ad1;
            float acc = 0.f;
#pragma unroll
            for (int c = 0; c < 16; ++c) acc += W1[d * 64 + h * 16 + c] * a[h * 16 + c];
            if (tid < 16) VA[q] = acc;
            else VD[q] = acc;
        }
        __syncthreads();
        int idx = ((int)blockIdx.x - gEdge) * 256 + tid;  // n*8+t
        if (idx >= T_STEPS * N_NODES) return;
        const float4 x = dyn[idx];
        float4 s4, d4;
#pragma unroll
        for (int h = 0; h < 4; ++h) {
            ((float*)&s4)[h] = x.x * VA[h] + x.y * VA[4 + h] + x.z * VA[8 + h] + x.w * VA[12 + h];
            ((float*)&d4)[h] = x.x * VD[h] + x.y * VD[4 + h] + x.z * VD[8 + h] + x.w * VD[12 + h];
        }
        asrc[idx] = s4;
        adst[idx] = d4;
    }
}

// ---------------- exclusive scan of cnt -> rowptr/cursor (1 block, 1024 thr) ----------------
__global__ void __launch_bounds__(1024) k_scan(const int* __restrict__ cnt,
                                               int* __restrict__ rowptr,
                                               int* __restrict__ cursor) {
    __shared__ int ssum[1024];
    const int CH = 10;  // 1024*10 >= 10000
    int tid = threadIdx.x;
    int base = tid * CH;
    int v[CH];
    int loc = 0;
#pragma unroll
    for (int i = 0; i < CH; ++i) {
        int idx = base + i;
        v[i] = (idx < N_NODES) ? cnt[idx] : 0;
        loc += v[i];
    }
    ssum[tid] = loc;
    __syncthreads();
    for (int st = 1; st < 1024; st <<= 1) {
        int val = (tid >= st) ? ssum[tid - st] : 0;
        __syncthreads();
        ssum[tid] += val;
        __syncthreads();
    }
    int run = ssum[tid] - loc;  // exclusive
#pragma unroll
    for (int i = 0; i < CH; ++i) {
        int idx = base + i;
        if (idx < N_NODES) {
            rowptr[idx] = run;
            cursor[idx] = run;
            run += v[i];
        }
    }
    if (tid == 1023) rowptr[N_NODES] = ssum[1023];
}

__global__ void k_scatter(const int* __restrict__ ei, int* __restrict__ cursor,
                          int* __restrict__ colsrc) {
    int idx = blockIdx.x * blockDim.x + threadIdx.x;
    if (idx >= ETOT) return;
    int src = (idx < E_EDGES) ? ei[idx] : (idx - E_EDGES);
    int dst = (idx < E_EDGES) ? ei[E_EDGES + idx] : (idx - E_EDGES);
    int pos = atomicAdd(&cursor[dst], 1);
    colsrc[pos] = src;
}

// ---------------- L1: one wave per node, lane = es*8 + t, two-pass chunk softmax ----------------
// u_h = sum_e w_e^h * x[src_e] (4-dim); out = (u_h @ W1)/s_h, ELU; fused W2 -> z2 bf16.
__global__ void __launch_bounds__(256) k_l1_node(
        const int* __restrict__ rowptr, const int* __restrict__ colsrc,
        const float4* __restrict__ asrc, const float4* __restrict__ adst,
        const float4* __restrict__ dyn, const float* __restrict__ W1,
        const float* __restrict__ b1, const float* __restrict__ W2,
        const float* __restrict__ as2, const float* __restrict__ ad2,
        unsigned short* __restrict__ z2g, float* __restrict__ asrc2,
        float* __restrict__ adst2) {
    __shared__ float sW1[256], sB1[64], sW2[64 * 32];
    __shared__ float sAs2[32], sAd2[32];
    __shared__ float sRow[4][8 * 65];
    int tid = threadIdx.x;
    for (int i = tid; i < 64 * 32; i += 256) sW2[i] = W2[i];
    if (tid < 256) sW1[tid] = W1[tid];
    if (tid < 64) sB1[tid] = b1[tid];
    if (tid < 32) { sAs2[tid] = as2[tid]; sAd2[tid] = ad2[tid]; }
    __syncthreads();

    int lane = tid & 63, wslot = tid >> 6;
    int n = blockIdx.x * 4 + wslot;
    int t = lane & 7, es = lane >> 3;
    int beg = rowptr[n];
    int deg = rowptr[n + 1] - beg;
    const float4 ad = adst[(n << 3) + t];

    float m0 = -1e30f, m1 = -1e30f, m2 = -1e30f, m3 = -1e30f;
    float s0 = 0.f, s1 = 0.f, s2 = 0.f, s3 = 0.f;
    float u[16];
#pragma unroll
    for (int i = 0; i < 16; ++i) u[i] = 0.f;

    for (int cb = 0; cb < deg; cb += 24) {
        int cn = deg - cb;
        if (cn > 24) cn = 24;
        int R = (cn + 7) >> 3;
        float4 lr[3], xr[3];
#pragma unroll
        for (int r = 0; r < 3; ++r) {
            lr[r] = make_float4(-1e30f, -1e30f, -1e30f, -1e30f);
            xr[r] = make_float4(0.f, 0.f, 0.f, 0.f);
        }
#pragma unroll
        for (int r = 0; r < 3; ++r) {
            if (r < R) {
                int e = cb + r * 8 + es;
                bool act = e < deg;
                int src = colsrc[beg + (act ? e : 0)];
                const float4 as = asrc[(src << 3) + t];
                const float4 x4 = dyn[(src << 3) + t];
                if (act) {
                    lr[r].x = lrelu(as.x + ad.x);
                    lr[r].y = lrelu(as.y + ad.y);
                    lr[r].z = lrelu(as.z + ad.z);
                    lr[r].w = lrelu(as.w + ad.w);
                    xr[r] = x4;
                }
            }
        }
        // chunk max per head, single wave-reduction
        float c0 = fmaxf(fmaxf(lr[0].x, lr[1].x), lr[2].x);
        float c1 = fmaxf(fmaxf(lr[0].y, lr[1].y), lr[2].y);
        float c2 = fmaxf(fmaxf(lr[0].z, lr[1].z), lr[2].z);
        float c3 = fmaxf(fmaxf(lr[0].w, lr[1].w), lr[2].w);
        c0 = g8max(c0); c1 = g8max(c1); c2 = g8max(c2); c3 = g8max(c3);
        float nm0 = fmaxf(m0, c0), nm1 = fmaxf(m1, c1);
        float nm2 = fmaxf(m2, c2), nm3 = fmaxf(m3, c3);
        float f0 = expf(m0 - nm0), f1 = expf(m1 - nm1);
        float f2 = expf(m2 - nm2), f3 = expf(m3 - nm3);
        m0 = nm0; m1 = nm1; m2 = nm2; m3 = nm3;
#pragma unroll
        for (int i = 0; i < 16; ++i) u[i] *= (i < 4) ? f0 : (i < 8) ? f1 : (i < 12) ? f2 : f3;
        float ws0 = 0.f, ws1 = 0.f, ws2 = 0.f, ws3 = 0.f;
#pragma unroll
        for (int r = 0; r < 3; ++r) {
            float w0 = expf(lr[r].x - m0);
            float w1 = expf(lr[r].y - m1);
            float w2 = expf(lr[r].z - m2);
            float w3 = expf(lr[r].w - m3);
            ws0 += w0; ws1 += w1; ws2 += w2; ws3 += w3;
            u[0] += w0 * xr[r].x; u[1] += w0 * xr[r].y; u[2] += w0 * xr[r].z; u[3] += w0 * xr[r].w;
            u[4] += w1 * xr[r].x; u[5] += w1 * xr[r].y; u[6] += w1 * xr[r].z; u[7] += w1 * xr[r].w;
            u[8] += w2 * xr[r].x; u[9] += w2 * xr[r].y; u[10] += w2 * xr[r].z; u[11] += w2 * xr[r].w;
            u[12] += w3 * xr[r].x; u[13] += w3 * xr[r].y; u[14] += w3 * xr[r].z; u[15] += w3 * xr[r].w;
        }
        s0 = s0 * f0 + g8sum(ws0);
        s1 = s1 * f1 + g8sum(ws1);
        s2 = s2 * f2 + g8sum(ws2);
        s3 = s3 * f3 + g8sum(ws3);
    }
    // reduce u over the 8 es-lanes (per t)
#pragma unroll
    for (int i = 0; i < 16; ++i) {
        float v = u[i];
        v += __shfl_xor(v, 8);
        v += __shfl_xor(v, 16);
        v += __shfl_xor(v, 32);
        u[i] = v;
    }
    // epilogue: lane covers channels c = es*8+j (head h = es>>1 fixed per lane)
    int h = es >> 1;
    float uh0 = (h == 0) ? u[0] : (h == 1) ? u[4] : (h == 2) ? u[8] : u[12];
    float uh1 = (h == 0) ? u[1] : (h == 1) ? u[5] : (h == 2) ? u[9] : u[13];
    float uh2 = (h == 0) ? u[2] : (h == 1) ? u[6] : (h == 2) ? u[10] : u[14];
    float uh3 = (h == 0) ? u[3] : (h == 1) ? u[7] : (h == 2) ? u[11] : u[15];
    float sh = (h == 0) ? s0 : (h == 1) ? s1 : (h == 2) ? s2 : s3;
    float inv = 1.f / sh;
#pragma unroll
    for (int j = 0; j < 8; ++j) {
        int c = es * 8 + j;
        float acc = uh0 * sW1[c] + uh1 * sW1[64 + c] + uh2 * sW1[128 + c] + uh3 * sW1[192 + c];
        sRow[wslot][t * 65 + c] = eluf(acc * inv + sB1[c]);
    }
    __syncthreads();
    // fused W2 projection: lane computes k = es*4 .. es*4+3 for its t
    float z0 = 0.f, z1v = 0.f, z2v = 0.f, z3v = 0.f;
#pragma unroll 8
    for (int j = 0; j < 64; ++j) {
        float r = sRow[wslot][t * 65 + j];
        const float4 w4 = *reinterpret_cast<const float4*>(&sW2[j * 32 + es * 4]);
        z0 += r * w4.x; z1v += r * w4.y; z2v += r * w4.z; z3v += r * w4.w;
    }
    int wid8 = (n << 3) + t;
    unsigned int p0 = (unsigned)f2bf(z0) | ((unsigned)f2bf(z1v) << 16);
    unsigned int p1 = (unsigned)f2bf(z2v) | ((unsigned)f2bf(z3v) << 16);
    *reinterpret_cast<uint2*>(z2g + (size_t)wid8 * 32 + es * 4) = make_uint2(p0, p1);
    float pa = z0 * sAs2[es * 4] + z1v * sAs2[es * 4 + 1] + z2v * sAs2[es * 4 + 2] + z3v * sAs2[es * 4 + 3];
    float pd = z0 * sAd2[es * 4] + z1v * sAd2[es * 4 + 1] + z2v * sAd2[es * 4 + 2] + z3v * sAd2[es * 4 + 3];
    pa = g8sum(pa);
    pd = g8sum(pd);
    if (es == 0) { asrc2[wid8] = pa; adst2[wid8] = pd; }
}

// ---------------- L2: one wave per node; phase A logits->LDS, phase B coalesced z2 rows ----------
__global__ void __launch_bounds__(256) k_l2_node(
        const int* __restrict__ rowptr, const int* __restrict__ colsrc,
        const float* __restrict__ asrc, const float* __restrict__ adst,
        const unsigned short* __restrict__ z2, const float* __restrict__ b2,
        float* __restrict__ part) {
    __shared__ int sSrc[4][64];
    __shared__ float sW[4][64 * 8];  // [e][t]
    __shared__ float sF[4][8], sS[4][8];
    __shared__ float sB2[32];
    __shared__ float sPart[256];
    int tid = threadIdx.x;
    if (tid < 32) sB2[tid] = b2[tid];
    sPart[tid] = 0.f;
    __syncthreads();

    int lane = tid & 63, wslot = tid >> 6;
    int n = blockIdx.x * 4 + wslot;
    int t = lane & 7, es = lane >> 3;      // phase A mapping
    int t2 = lane >> 3, cg = lane & 7;     // phase B mapping (t2, 4-ch group)
    int beg = rowptr[n];
    int deg = rowptr[n + 1] - beg;
    float ad = adst[(n << 3) + t];
    const unsigned short* zb = z2 + t2 * 32 + cg * 4;  // + src*256

    float m = -1e30f, s = 0.f;
    float a0 = 0.f, a1 = 0.f, a2 = 0.f, a3 = 0.f;
    for (int cb = 0; cb < deg; cb += 64) {
        int cn = deg - cb;
        if (cn > 64) cn = 64;
        int R = (cn + 7) >> 3;
        float lr[8];
#pragma unroll
        for (int r = 0; r < 8; ++r) {
            lr[r] = -1e30f;
            if (r < R) {
                int e = cb + r * 8 + es;
                bool act = e < deg;
                int src = colsrc[beg + (act ? e : 0)];
                if (act) lr[r] = lrelu(asrc[(src << 3) + t] + ad);
                if (t == 0) sSrc[wslot][r * 8 + es] = src;
            }
        }
        float lm = lr[0];
#pragma unroll
        for (int r = 1; r < 8; ++r) lm = fmaxf(lm, lr[r]);
        lm = g8max(lm);
        float nm = fmaxf(m, lm);
        float f = expf(m - nm);
        m = nm;
        float ws = 0.f;
#pragma unroll
        for (int r = 0; r < 8; ++r) {
            if (r < R) {
                float w = expf(lr[r] - nm);
                ws += w;
                sW[wslot][(r * 8 + es) * 8 + t] = w;
            }
        }
        s = s * f + g8sum(ws);
        if (es == 0) sF[wslot][t] = f;
        // phase B: accumulate this chunk, lane = (t2, cg)
        float fb = sF[wslot][t2];
        a0 *= fb; a1 *= fb; a2 *= fb; a3 *= fb;
        for (int e = 0; e < cn; ++e) {
            int src = sSrc[wslot][e];
            float w = sW[wslot][e * 8 + t2];
            uint2 pz = *reinterpret_cast<const uint2*>(zb + (size_t)src * 256);
            a0 += w * bf2f(pz.x & 0xFFFFu);
            a1 += w * bf2f(pz.x >> 16);
            a2 += w * bf2f(pz.y & 0xFFFFu);
            a3 += w * bf2f(pz.y >> 16);
        }
    }
    if (es == 0) sS[wslot][t] = s;
    float invs = 1.f / sS[wslot][t2];
    int cbase = cg * 4;
    float v0 = eluf(a0 * invs + sB2[cbase]);
    float v1 = eluf(a1 * invs + sB2[cbase + 1]);
    float v2 = eluf(a2 * invs + sB2[cbase + 2]);
    float v3 = eluf(a3 * invs + sB2[cbase + 3]);
    int pidx = t2 * 32 + cbase;
    atomicAdd(&sPart[pidx], v0);
    atomicAdd(&sPart[pidx + 1], v1);
    atomicAdd(&sPart[pidx + 2], v2);
    atomicAdd(&sPart[pidx + 3], v3);
    __syncthreads();
    atomicAdd(&part[((blockIdx.x & (NREP - 1)) << 8) + tid], sPart[tid]);
}

// ---------------- replica-reduce + GRU + heads + SIR (single block, 128 thr) ----------------
__global__ void k_head(const float* __restrict__ part, const float* __restrict__ h0,
                       const float* __restrict__ W_ih, const float* __restrict__ W_hh,
                       const float* __restrict__ b_ih, const float* __restrict__ b_hh,
                       const float* __restrict__ Wi, const float* __restrict__ bi,
                       const float* __restrict__ Wr, const float* __restrict__ br,
                       const float* __restrict__ Ws, const float* __restrict__ bs,
                       const float* __restrict__ cI, const float* __restrict__ cR,
                       const float* __restrict__ Nptr, const float* __restrict__ Ivec,
                       const float* __restrict__ Rvec, float* __restrict__ out) {
    __shared__ float xs[256];  // cur_h [8][32]
    __shared__ float h[32], gi[96], gh[96], hnew[32], hs[T_STEPS * 32], sirv[16];
    const float invN = 1.0f / (float)N_NODES;
    int j = threadIdx.x;
#pragma unroll
    for (int p = 0; p < 2; ++p) {
        int e = j + p * 128;
        float sum = 0.f;
        for (int r = 0; r < NREP; ++r) sum += part[r * 256 + e];
        xs[e] = sum * invN;
    }
    if (j < 32) h[j] = h0[j];
    __syncthreads();
    for (int t = 0; t < T_STEPS; ++t) {
        if (j < 96) {
            float accI = b_ih[j], accH = b_hh[j];
            for (int k = 0; k < 32; ++k) {
                accI += W_ih[j * 32 + k] * xs[t * 32 + k];
                accH += W_hh[j * 32 + k] * h[k];
            }
            gi[j] = accI;
            gh[j] = accH;
        }
        __syncthreads();
        if (j < 32) {
            float r = sigmoidf(gi[j] + gh[j]);
            float zg = sigmoidf(gi[32 + j] + gh[32 + j]);
            float ng = tanhf(gi[64 + j] + r * gh[64 + j]);
            hnew[j] = (1.f - zg) * ng + zg * h[j];
        }
        __syncthreads();
        if (j < 32) {
            h[j] = hnew[j];
            hs[t * 32 + j] = hnew[j];
        }
        __syncthreads();
    }
    if (j < 32) out[512 + j] = h[j];  // h_final
    {
        int t = j >> 4, p = j & 15;
        float accI = bi[p], accR = br[p];
        for (int k = 0; k < 34; ++k) {
            float hck = (k < 32) ? hs[t * 32 + k] : (k == 32 ? cI[t] : cR[t]);
            accI += hck * Wi[p * 34 + k];
            accR += hck * Wr[p * 34 + k];
        }
        out[j] = accI;
        out[128 + j] = accR;
    }
    if (j < 16) {
        int t = j >> 1, q = j & 1;
        float acc = bs[q];
        for (int k = 0; k < 34; ++k) {
            float hck = (k < 32) ? hs[t * 32 + k] : (k == 32 ? cI[t] : cR[t]);
            acc += hck * Ws[q * 34 + k];
        }
        sirv[j] = acc;
    }
    __syncthreads();
    if (j < 8) {
        int t = j;
        float alpha = sigmoidf(sirv[2 * t]);
        float beta = sigmoidf(sirv[2 * t + 1]);
        float Np = Nptr[0];
        float lI = Ivec[t], lR = Rvec[t];
        for (int p = 0; p < PW; ++p) {
            float lS = Np - lI - lR;
            float dI = alpha * lI * (lS / Np) - beta * lI;
            float dR = beta * lI;
            out[256 + t * 16 + p] = dI;
            out[384 + t * 16 + p] = dR;
            lI += dI;
            lR += dR;
        }
    }
}

extern "C" void kernel_launch(void* const* d_in, const int* in_sizes, int n_in,
                              void* d_out, int out_size, void* d_ws, size_t ws_size,
                              hipStream_t stream) {
    const float* dyn = (const float*)d_in[0];
    const float* cI = (const float*)d_in[1];
    const float* cR = (const float*)d_in[2];
    const float* Nptr = (const float*)d_in[3];
    const float* Ivec = (const float*)d_in[4];
    const float* Rvec = (const float*)d_in[5];
    const int* ei = (const int*)d_in[6];
    const float* h0 = (const float*)d_in[7];
    const float* W1 = (const float*)d_in[8];
    const float* as1 = (const float*)d_in[9];
    const float* ad1 = (const float*)d_in[10];
    const float* b1 = (const float*)d_in[11];
    const float* W2 = (const float*)d_in[12];
    const float* as2 = (const float*)d_in[13];
    const float* ad2 = (const float*)d_in[14];
    const float* b2 = (const float*)d_in[15];
    const float* W_ih = (const float*)d_in[16];
    const float* W_hh = (const float*)d_in[17];
    const float* b_ih = (const float*)d_in[18];
    const float* b_hh = (const float*)d_in[19];
    const float* Wi = (const float*)d_in[20];
    const float* bi = (const float*)d_in[21];
    const float* Wr = (const float*)d_in[22];
    const float* br = (const float*)d_in[23];
    const float* Ws = (const float*)d_in[24];
    const float* bs = (const float*)d_in[25];
    float* out = (float*)d_out;

    char* ws = (char*)d_ws;
    size_t off = 0;
    auto alloc = [&](size_t bytes) {
        void* p = ws + off;
        off += (bytes + 255) & ~(size_t)255;
        return p;
    };
    const size_t TN = (size_t)T_STEPS * N_NODES;
    // cnt and part adjacent -> single memset
    int* cnt = (int*)alloc((N_NODES + 1) * 4);
    float* part = (float*)alloc((size_t)NREP * 256 * 4);
    size_t zero_bytes = off;
    float4* asrc1 = (float4*)alloc(TN * 16);
    float4* adst1 = (float4*)alloc(TN * 16);
    unsigned short* z2 = (unsigned short*)alloc(TN * 32 * 2);
    float* asrc2 = (float*)alloc(TN * 4);
    float* adst2 = (float*)alloc(TN * 4);
    int* rowptr = (int*)alloc((N_NODES + 1) * 4);
    int* cursor = (int*)alloc(N_NODES * 4);
    int* colsrc = (int*)alloc((size_t)ETOT * 4);
    (void)ws_size; (void)in_sizes; (void)n_in; (void)out_size;

    const int BT = 256;
    hipMemsetAsync(cnt, 0, zero_bytes, stream);
    int gEdge = (ETOT + BT - 1) / BT;               // 665
    int gNode = (int)((TN + BT - 1) / BT);          // 313
    k_count_att<<<gEdge + gNode, BT, 0, stream>>>(ei, cnt, (const float4*)dyn, W1, as1, ad1,
                                                  asrc1, adst1, gEdge);
    k_scan<<<1, 1024, 0, stream>>>(cnt, rowptr, cursor);
    k_scatter<<<gEdge, BT, 0, stream>>>(ei, cursor, colsrc);
    k_l1_node<<<N_NODES / 4, BT, 0, stream>>>(rowptr, colsrc, asrc1, adst1,
                                              (const float4*)dyn, W1, b1, W2, as2, ad2,
                                              z2, asrc2, adst2);
    k_l2_node<<<N_NODES / 4, BT, 0, stream>>>(rowptr, colsrc, asrc2, adst2, z2, b2, part);
    k_head<<<1, 128, 0, stream>>>(part, h0, W_ih, W_hh, b_ih, b_hh, Wi, bi, Wr, br, Ws, bs,
                                  cI, cR, Nptr, Ivec, Rvec, out);
}